// Round 4
// baseline (814.777 us; speedup 1.0000x reference)
//
#include <hip/hip_runtime.h>
#include <hip/hip_bf16.h>
#include <math.h>

#define T 2048
#define HID 4096
#define NH 32
#define NKV 8
#define DH 128
#define QKV_N 6144
#define SCALE_F 0.08838834764831845f
#define NEGV -1e9f

typedef unsigned short u16t;
typedef __attribute__((ext_vector_type(8))) short bf8;
typedef __attribute__((ext_vector_type(4))) float f4;

__device__ __forceinline__ float bf2f(u16t x) {
  unsigned int u = ((unsigned int)x) << 16;
  return __builtin_bit_cast(float, u);
}
__device__ __forceinline__ u16t f2bf(float f) {
  unsigned int u = __builtin_bit_cast(unsigned int, f);
  u += 0x7fffu + ((u >> 16) & 1u);
  return (u16t)(u >> 16);
}

// Load 8 consecutive elements as bf16 from either a bf16 or f32 source (compile-time).
template <int F32>
__device__ __forceinline__ bf8 load8(const void* p, size_t idx) {
  if (F32) {
    const f4* fp = (const f4*)((const float*)p + idx);
    f4 a = fp[0], b = fp[1];
    bf8 r;
    r[0] = (short)f2bf(a[0]); r[1] = (short)f2bf(a[1]);
    r[2] = (short)f2bf(a[2]); r[3] = (short)f2bf(a[3]);
    r[4] = (short)f2bf(b[0]); r[5] = (short)f2bf(b[1]);
    r[6] = (short)f2bf(b[2]); r[7] = (short)f2bf(b[3]);
    return r;
  }
  return *(const bf8*)((const u16t*)p + idx);
}

// ---------------- GEMM: C[M][N] = A[M][K] * B[N][K]^T ------------------------
// 128x128 block tile, 4 waves 2x2 (64x64 each), BK=64, padded LDS stride 72.
// A32/B32: operand source dtype (1=f32, 0=bf16). OUT32: output dtype.
template <int A32, int B32, int OUT32>
__global__ __launch_bounds__(256) void gemm_bt(const void* __restrict__ A,
                                               const void* __restrict__ B,
                                               void* __restrict__ C, int N, int K) {
  constexpr int LDT = 72;
  __shared__ u16t As[128 * LDT];
  __shared__ u16t Bs[128 * LDT];
  const int tid = threadIdx.x;
  const int wave = tid >> 6, lane = tid & 63;
  const int l15 = lane & 15, quad = lane >> 4;
  const int m0 = blockIdx.y * 128, n0 = blockIdx.x * 128;
  const int wm = (wave & 1) * 64, wn = (wave >> 1) * 64;

  f4 acc[4][4];
#pragma unroll
  for (int i = 0; i < 4; i++)
#pragma unroll
    for (int j = 0; j < 4; j++) acc[i][j] = (f4){0.f, 0.f, 0.f, 0.f};

  for (int k0 = 0; k0 < K; k0 += 64) {
    __syncthreads();
#pragma unroll
    for (int i = 0; i < 4; i++) {
      int c = tid + 256 * i;           // 1024 chunks of 8 elems
      int r = c >> 3, kc = (c & 7) << 3;
      *(bf8*)&As[r * LDT + kc] = load8<A32>(A, (size_t)(m0 + r) * K + k0 + kc);
      *(bf8*)&Bs[r * LDT + kc] = load8<B32>(B, (size_t)(n0 + r) * K + k0 + kc);
    }
    __syncthreads();
#pragma unroll
    for (int kq = 0; kq < 2; kq++) {
      bf8 af[4], bfr[4];
#pragma unroll
      for (int mt = 0; mt < 4; mt++)
        af[mt] = *(const bf8*)&As[(wm + mt * 16 + l15) * LDT + kq * 32 + quad * 8];
#pragma unroll
      for (int nt = 0; nt < 4; nt++)
        bfr[nt] = *(const bf8*)&Bs[(wn + nt * 16 + l15) * LDT + kq * 32 + quad * 8];
#pragma unroll
      for (int mt = 0; mt < 4; mt++)
#pragma unroll
        for (int nt = 0; nt < 4; nt++)
          acc[mt][nt] = __builtin_amdgcn_mfma_f32_16x16x32_bf16(af[mt], bfr[nt], acc[mt][nt], 0, 0, 0);
    }
  }
#pragma unroll
  for (int mt = 0; mt < 4; mt++)
#pragma unroll
    for (int nt = 0; nt < 4; nt++)
#pragma unroll
      for (int r = 0; r < 4; r++) {
        int row = m0 + wm + mt * 16 + quad * 4 + r;
        int col = n0 + wn + nt * 16 + l15;
        if (OUT32)
          ((float*)C)[(size_t)row * N + col] = acc[mt][nt][r];
        else
          ((u16t*)C)[(size_t)row * N + col] = f2bf(acc[mt][nt][r]);
      }
}

// ---------------- Prep: RoPE q/k, gate, repack k_global ------------------------
__global__ __launch_bounds__(256) void prep_kernel(
    const int* __restrict__ positions, const u16t* __restrict__ qkv,
    const float* __restrict__ kg_in, const float* __restrict__ wg,
    const float* __restrict__ bg, u16t* __restrict__ Qr, u16t* __restrict__ Kl,
    u16t* __restrict__ KG, float* __restrict__ gate) {
  const int t = blockIdx.x, tid = threadIdx.x;
  const float pos = (float)positions[t];
  const u16t* row = qkv + (size_t)t * QKV_N;
  // Q rope + gate partial: pair p = h*64 + dp, 8 pairs/thread, head = tid/8
  float gp = 0.f;
#pragma unroll
  for (int i = 0; i < 8; i++) {
    int p = tid * 8 + i;
    int h = p >> 6, dp = p & 63;
    float invf = exp2f(-0.20762050593045702f * (float)dp);  // 10000^(-dp/64)
    float f = pos * invf;
    float c = cosf(f), s = sinf(f);
    float x1 = bf2f(row[h * DH + dp]);
    float x2 = bf2f(row[h * DH + dp + 64]);
    float o1 = x1 * c - x2 * s;
    float o2 = x2 * c + x1 * s;
    Qr[(size_t)t * HID + h * DH + dp] = f2bf(o1);
    Qr[(size_t)t * HID + h * DH + dp + 64] = f2bf(o2);
    gp += o1 * wg[h * DH + dp] + o2 * wg[h * DH + dp + 64];
  }
  gp += __shfl_xor(gp, 1, 64);
  gp += __shfl_xor(gp, 2, 64);
  gp += __shfl_xor(gp, 4, 64);
  if ((tid & 7) == 0) {
    int h = tid >> 3;
    gate[t * NH + h] = 1.f / (1.f + expf(-(gp + bg[h])));
  }
  // K rope: 512 pairs, 2/thread
  const u16t* krow = row + HID;
#pragma unroll
  for (int i = 0; i < 2; i++) {
    int p = tid * 2 + i;
    int g = p >> 6, dp = p & 63;
    float invf = exp2f(-0.20762050593045702f * (float)dp);
    float f = pos * invf;
    float c = cosf(f), s = sinf(f);
    float x1 = bf2f(krow[g * DH + dp]);
    float x2 = bf2f(krow[g * DH + dp + 64]);
    Kl[(size_t)g * T * DH + t * DH + dp] = f2bf(x1 * c - x2 * s);
    Kl[(size_t)g * T * DH + t * DH + dp + 64] = f2bf(x2 * c + x1 * s);
  }
  // repack k_global -> KG[g][t][d]
  {
    int d4 = tid * 4;
    int g = d4 >> 7, d = d4 & 127;
    const float* src = kg_in + (size_t)t * (NKV * DH) + d4;
    u16t* dst = KG + (size_t)g * T * DH + t * DH + d;
    dst[0] = f2bf(src[0]); dst[1] = f2bf(src[1]);
    dst[2] = f2bf(src[2]); dst[3] = f2bf(src[3]);
  }
}

// ---------------- Transpose: out[g][d][t] = in[t*istride + coff + g*128 + d] ---
template <int F32>
__global__ __launch_bounds__(256) void transpose_gd(const void* __restrict__ in,
                                                    u16t* __restrict__ out,
                                                    int istride, int coff) {
  __shared__ u16t tile[64][72];
  const int g = blockIdx.z;
  const int t0 = blockIdx.x * 64, d0 = blockIdx.y * 64;
  u16t* dst = out + (size_t)g * DH * T;
  const int tid = threadIdx.x;
#pragma unroll
  for (int i = 0; i < 2; i++) {
    int c = tid + 256 * i;           // 512 chunks
    int r = c >> 3, dch = (c & 7) << 3;
    size_t idx = (size_t)coff + g * DH + (size_t)(t0 + r) * istride + d0 + dch;
    *(bf8*)&tile[r][dch] = load8<F32>(in, idx);
  }
  __syncthreads();
#pragma unroll
  for (int i = 0; i < 2; i++) {
    int c = tid + 256 * i;
    int d = c >> 3, tch = (c & 7) << 3;
    bf8 v;
#pragma unroll
    for (int j = 0; j < 8; j++) v[j] = tile[tch + j][d];
    *(bf8*)&dst[(size_t)(d0 + d) * T + t0 + tch] = v;
  }
}

// ---------------- Flash attention (LOCAL=1: sliding window; 0: causal+combine) -
template <int LOCAL>
__global__ __launch_bounds__(256) void attn_kernel(
    const u16t* __restrict__ Qr, const u16t* __restrict__ Kbase,
    const u16t* __restrict__ VTbase, const float* __restrict__ gate,
    const u16t* __restrict__ oL, u16t* __restrict__ outp) {
  __shared__ u16t k_lds[64 * 136];   // [kv][d], pad 8
  __shared__ u16t v_lds[128 * 72];   // [d][kv], pad 8
  __shared__ u16t p_lds[128 * 72];   // [q][kv], pad 8
  const int h = blockIdx.x, qt = blockIdx.y;
  const int g = h >> 2;
  const int tid = threadIdx.x, wave = tid >> 6, lane = tid & 63;
  const int l15 = lane & 15, quad = lane >> 4;
  const int q0 = qt * 128 + wave * 32;
  const u16t* K = Kbase + (size_t)g * T * DH;   // [t][d]
  const u16t* VT = VTbase + (size_t)g * T * DH; // [d][t]

  bf8 qf[2][4];
#pragma unroll
  for (int mt = 0; mt < 2; mt++)
#pragma unroll
    for (int kq = 0; kq < 4; kq++)
      qf[mt][kq] = *(const bf8*)&Qr[(size_t)(q0 + mt * 16 + l15) * HID + h * DH + kq * 32 + quad * 8];

  f4 oacc[2][8];
  float m_st[2][4], l_st[2][4];
#pragma unroll
  for (int mt = 0; mt < 2; mt++) {
#pragma unroll
    for (int dt = 0; dt < 8; dt++) oacc[mt][dt] = (f4){0.f, 0.f, 0.f, 0.f};
#pragma unroll
    for (int r = 0; r < 4; r++) { m_st[mt][r] = -__builtin_inff(); l_st[mt][r] = 0.f; }
  }

  const int jend = 2 * qt + 2;
  const int jbeg = LOCAL ? (qt > 0 ? 2 * qt - 1 : 0) : 0;
  for (int j = jbeg; j < jend; j++) {
    const int kv0 = j * 64;
    __syncthreads();
#pragma unroll
    for (int i = 0; i < 4; i++) {
      int c = tid + 256 * i;  // 1024 chunks each
      int r = c >> 4, dch = (c & 15) << 3;
      *(bf8*)&k_lds[r * 136 + dch] = *(const bf8*)&K[(size_t)(kv0 + r) * DH + dch];
      int dd = c >> 3, kch = (c & 7) << 3;
      *(bf8*)&v_lds[dd * 72 + kch] = *(const bf8*)&VT[(size_t)dd * T + kv0 + kch];
    }
    __syncthreads();
    // S = Q K^T  (per wave: 32 q rows x 64 kv)
    f4 s[2][4];
#pragma unroll
    for (int nt = 0; nt < 4; nt++) {
      bf8 kb[4];
#pragma unroll
      for (int kq = 0; kq < 4; kq++)
        kb[kq] = *(const bf8*)&k_lds[(nt * 16 + l15) * 136 + kq * 32 + quad * 8];
#pragma unroll
      for (int mt = 0; mt < 2; mt++) {
        f4 a = (f4){0.f, 0.f, 0.f, 0.f};
#pragma unroll
        for (int kq = 0; kq < 4; kq++)
          a = __builtin_amdgcn_mfma_f32_16x16x32_bf16(qf[mt][kq], kb[kq], a, 0, 0, 0);
        s[mt][nt] = a;
      }
    }
    // scale + mask
#pragma unroll
    for (int mt = 0; mt < 2; mt++)
#pragma unroll
      for (int nt = 0; nt < 4; nt++)
#pragma unroll
        for (int r = 0; r < 4; r++) {
          float v = s[mt][nt][r] * SCALE_F;
          int qq = q0 + mt * 16 + quad * 4 + r;
          int kk = kv0 + nt * 16 + l15;
          bool ok = LOCAL ? (kk <= qq && kk >= qq - 63) : (kk <= qq);
          s[mt][nt][r] = ok ? v : NEGV;
        }
    // online softmax stats
    float alpha[2][4], mn[2][4], rs[2][4];
#pragma unroll
    for (int mt = 0; mt < 2; mt++)
#pragma unroll
      for (int r = 0; r < 4; r++) {
        float rm = fmaxf(fmaxf(s[mt][0][r], s[mt][1][r]), fmaxf(s[mt][2][r], s[mt][3][r]));
        rm = fmaxf(rm, __shfl_xor(rm, 1, 64));
        rm = fmaxf(rm, __shfl_xor(rm, 2, 64));
        rm = fmaxf(rm, __shfl_xor(rm, 4, 64));
        rm = fmaxf(rm, __shfl_xor(rm, 8, 64));
        float m2 = fmaxf(m_st[mt][r], rm);
        alpha[mt][r] = __expf(m_st[mt][r] - m2);
        m_st[mt][r] = m2;
        mn[mt][r] = m2;
        rs[mt][r] = 0.f;
      }
#pragma unroll
    for (int mt = 0; mt < 2; mt++)
#pragma unroll
      for (int nt = 0; nt < 4; nt++)
#pragma unroll
        for (int r = 0; r < 4; r++) {
          float p = __expf(s[mt][nt][r] - mn[mt][r]);
          rs[mt][r] += p;
          p_lds[(wave * 32 + mt * 16 + quad * 4 + r) * 72 + nt * 16 + l15] = f2bf(p);
        }
#pragma unroll
    for (int mt = 0; mt < 2; mt++)
#pragma unroll
      for (int r = 0; r < 4; r++) {
        float t0 = rs[mt][r];
        t0 += __shfl_xor(t0, 1, 64);
        t0 += __shfl_xor(t0, 2, 64);
        t0 += __shfl_xor(t0, 4, 64);
        t0 += __shfl_xor(t0, 8, 64);
        l_st[mt][r] = l_st[mt][r] * alpha[mt][r] + t0;
      }
#pragma unroll
    for (int mt = 0; mt < 2; mt++)
#pragma unroll
      for (int dt = 0; dt < 8; dt++) {
        f4 o = oacc[mt][dt];
        o[0] *= alpha[mt][0]; o[1] *= alpha[mt][1];
        o[2] *= alpha[mt][2]; o[3] *= alpha[mt][3];
        oacc[mt][dt] = o;
      }
    __syncthreads();
    // PV: O += P V   (P a-frags from own wave's rows)
    bf8 pa[2][2];
#pragma unroll
    for (int mt = 0; mt < 2; mt++)
#pragma unroll
      for (int kq = 0; kq < 2; kq++)
        pa[mt][kq] = *(const bf8*)&p_lds[(wave * 32 + mt * 16 + l15) * 72 + kq * 32 + quad * 8];
#pragma unroll
    for (int dt = 0; dt < 8; dt++) {
      bf8 vb[2];
#pragma unroll
      for (int kq = 0; kq < 2; kq++)
        vb[kq] = *(const bf8*)&v_lds[(dt * 16 + l15) * 72 + kq * 32 + quad * 8];
#pragma unroll
      for (int mt = 0; mt < 2; mt++) {
        oacc[mt][dt] = __builtin_amdgcn_mfma_f32_16x16x32_bf16(pa[mt][0], vb[0], oacc[mt][dt], 0, 0, 0);
        oacc[mt][dt] = __builtin_amdgcn_mfma_f32_16x16x32_bf16(pa[mt][1], vb[1], oacc[mt][dt], 0, 0, 0);
      }
    }
  }
  // epilogue
#pragma unroll
  for (int mt = 0; mt < 2; mt++)
#pragma unroll
    for (int r = 0; r < 4; r++) {
      int tq = q0 + mt * 16 + quad * 4 + r;
      float inv_l = 1.f / l_st[mt][r];
      if (LOCAL) {
#pragma unroll
        for (int dt = 0; dt < 8; dt++) {
          int col = dt * 16 + l15;
          outp[(size_t)tq * HID + h * DH + col] = f2bf(oacc[mt][dt][r] * inv_l);
        }
      } else {
        float gt = gate[tq * NH + h];
#pragma unroll
        for (int dt = 0; dt < 8; dt++) {
          int col = dt * 16 + l15;
          float ov = oacc[mt][dt][r] * inv_l;
          float ol = bf2f(oL[(size_t)tq * HID + h * DH + col]);
          outp[(size_t)tq * HID + h * DH + col] = f2bf(ov * gt + ol * (1.f - gt));
        }
      }
    }
}

extern "C" void kernel_launch(void* const* d_in, const int* in_sizes, int n_in,
                              void* d_out, int out_size, void* d_ws, size_t ws_size,
                              hipStream_t stream) {
  (void)in_sizes; (void)n_in; (void)out_size; (void)ws_size;
  const int* positions = (const int*)d_in[0];
  const void* hidden = d_in[1];        // f32 [T][HID]
  const float* k_global = (const float*)d_in[2];  // f32 [T][NKV][DH]
  const void* v_global = d_in[3];      // f32 [T][NKV][DH]
  const void* w_qkv = d_in[4];         // f32 [QKV_N][HID]
  const void* w_o = d_in[5];           // f32 [HID][HID]
  const float* w_gate = (const float*)d_in[6];    // f32 [NH][DH]
  const float* b_gate = (const float*)d_in[7];    // f32 [NH]
  float* out = (float*)d_out;          // f32 [T][HID]

  char* ws = (char*)d_ws;
  size_t off = 0;
  u16t* qkv = (u16t*)(ws + off); off += (size_t)T * QKV_N * 2;
  u16t* Qr  = (u16t*)(ws + off); off += (size_t)T * HID * 2;
  u16t* Kl  = (u16t*)(ws + off); off += (size_t)NKV * T * DH * 2;
  u16t* KG  = (u16t*)(ws + off); off += (size_t)NKV * T * DH * 2;
  u16t* VlT = (u16t*)(ws + off); off += (size_t)NKV * T * DH * 2;
  u16t* VGT = (u16t*)(ws + off); off += (size_t)NKV * T * DH * 2;
  float* gateb = (float*)(ws + off); off += (size_t)T * NH * 4;
  u16t* out_l = (u16t*)(ws + off); off += (size_t)T * HID * 2;
  u16t* out_c = (u16t*)(ws + off); off += (size_t)T * HID * 2;

  // 1) qkv = hidden @ w_qkv^T   (f32 in, bf16 out)
  gemm_bt<1, 1, 0><<<dim3(QKV_N / 128, T / 128), 256, 0, stream>>>(hidden, w_qkv, qkv, QKV_N, HID);
  // 2) rope q/k, gate, repack k_global
  prep_kernel<<<T, 256, 0, stream>>>(positions, qkv, k_global, w_gate, b_gate, Qr, Kl, KG, gateb);
  // 3) transpose V's to [g][d][t]
  transpose_gd<0><<<dim3(T / 64, DH / 64, NKV), 256, 0, stream>>>(qkv, VlT, QKV_N, HID + NKV * DH);
  transpose_gd<1><<<dim3(T / 64, DH / 64, NKV), 256, 0, stream>>>(v_global, VGT, NKV * DH, 0);
  // 4) local sliding-window attention -> out_l
  attn_kernel<1><<<dim3(NH, T / 128), 256, 0, stream>>>(Qr, Kl, VlT, nullptr, nullptr, out_l);
  // 5) global causal attention + gate-combine -> out_c
  attn_kernel<0><<<dim3(NH, T / 128), 256, 0, stream>>>(Qr, KG, VGT, gateb, out_l, out_c);
  // 6) final = out_c @ w_o^T    (bf16 x f32 in, f32 out)
  gemm_bt<0, 1, 1><<<dim3(HID / 128, T / 128), 256, 0, stream>>>(out_c, w_o, out, HID, HID);
}